// Round 2
// baseline (399.077 us; speedup 1.0000x reference)
//
#include <hip/hip_runtime.h>
#include <hip/hip_bf16.h>

// Problem: gates = x @ W_ih^T + b_ih + b_hh ; c = sig(i)*tanh(g); h = sig(o)*tanh(c)
// x: (131072, 128) f32, W_ih: (1024, 128) f32 (only rows 0-255, 512-1023 used)
// out: h (131072,256) f32 then c (131072,256) f32.

#define M_TOTAL (64 * 2048)   // 131072 rows
#define K_DIM   128
#define N_OUT   256
#define NBLOCKS 1024          // 4 waves/block -> 4096 waves -> 512 row-groups

typedef __bf16 bf16x8 __attribute__((ext_vector_type(8)));
typedef float  f32x16 __attribute__((ext_vector_type(16)));

static __device__ __forceinline__ bf16x8 cvt8(float4 a, float4 b) {
    bf16x8 r;
    r[0] = (__bf16)a.x; r[1] = (__bf16)a.y; r[2] = (__bf16)a.z; r[3] = (__bf16)a.w;
    r[4] = (__bf16)b.x; r[5] = (__bf16)b.y; r[6] = (__bf16)b.z; r[7] = (__bf16)b.w;
    return r;
}

static __device__ __forceinline__ float fast_sigmoid(float x) {
    // 1/(1+exp(-x)); exp->inf gives 0, exp->0 gives 1. No NaN.
    float e = __expf(-x);
    return __builtin_amdgcn_rcpf(1.0f + e);
}

static __device__ __forceinline__ float fast_tanh(float x) {
    // 1 - 2/(exp(2x)+1); x->+inf: 1-0=1, x->-inf: 1-2=-1. No NaN.
    float e = __expf(2.0f * x);
    return 1.0f - 2.0f * __builtin_amdgcn_rcpf(e + 1.0f);
}

__global__ __launch_bounds__(256, 2)
void lstm_gates_kernel(const float* __restrict__ x,
                       const float* __restrict__ Wih,
                       const float* __restrict__ bih,
                       const float* __restrict__ bhh,
                       float* __restrict__ hout,
                       float* __restrict__ cout)
{
    const int lane  = threadIdx.x & 63;
    const int wid   = threadIdx.x >> 6;
    const int gw    = blockIdx.x * 4 + wid;      // global wave id
    const int cs    = gw & 7;                    // column slice (32 cols each)
    const int grp   = gw >> 3;                   // row group
    const int ngrp  = (NBLOCKS * 4) >> 3;        // 512

    const int c0    = cs * 32;
    const int ln31  = lane & 31;
    const int khalf = (lane >> 5) * 8;           // k offset per half-wave: 0 or 8

    // ---- Load W_ih fragments for 3 gates (i, g, o), kept in registers ----
    // B frag layout (32x32x16): col = lane&31, k = kk*16 + (lane>>5)*8 + j
    // (any consistent A/B k-placement bijection is valid: MFMA pairs slots)
    bf16x8 bi[8], bg[8], bo[8];
    {
        const float4* wi = (const float4*)(Wih + (size_t)(0   + c0 + ln31) * K_DIM + khalf);
        const float4* wg = (const float4*)(Wih + (size_t)(512 + c0 + ln31) * K_DIM + khalf);
        const float4* wo = (const float4*)(Wih + (size_t)(768 + c0 + ln31) * K_DIM + khalf);
        #pragma unroll
        for (int kk = 0; kk < 8; ++kk) {
            // row stride = 128 f32 = 32 float4; k step = 16 f32 = 4 float4
            bi[kk] = cvt8(wi[kk * 4], wi[kk * 4 + 1]);
            bg[kk] = cvt8(wg[kk * 4], wg[kk * 4 + 1]);
            bo[kk] = cvt8(wo[kk * 4], wo[kk * 4 + 1]);
        }
    }
    const float bias_i = bih[0   + c0 + ln31] + bhh[0   + c0 + ln31];
    const float bias_g = bih[512 + c0 + ln31] + bhh[512 + c0 + ln31];
    const float bias_o = bih[768 + c0 + ln31] + bhh[768 + c0 + ln31];

    for (int t = grp; t < M_TOTAL / 32; t += ngrp) {
        const int m0 = t * 32;
        // A frag layout: row = m0 + (lane&31), k = kk*16 + (lane>>5)*8 + j
        const float4* ap = (const float4*)(x + (size_t)(m0 + ln31) * K_DIM + khalf);
        bf16x8 a[8];
        #pragma unroll
        for (int kk = 0; kk < 8; ++kk)
            a[kk] = cvt8(ap[kk * 4], ap[kk * 4 + 1]);

        f32x16 ai = (f32x16)0.0f, ag = (f32x16)0.0f, ao = (f32x16)0.0f;
        #pragma unroll
        for (int kk = 0; kk < 8; ++kk) {
            ai = __builtin_amdgcn_mfma_f32_32x32x16_bf16(a[kk], bi[kk], ai, 0, 0, 0);
            ag = __builtin_amdgcn_mfma_f32_32x32x16_bf16(a[kk], bg[kk], ag, 0, 0, 0);
            ao = __builtin_amdgcn_mfma_f32_32x32x16_bf16(a[kk], bo[kk], ao, 0, 0, 0);
        }

        // Epilogue: C/D layout col = c0 + (lane&31), row = m0 + (r&3) + 8*(r>>2) + 4*(lane>>5)
        #pragma unroll
        for (int r = 0; r < 16; ++r) {
            const int row = m0 + (r & 3) + 8 * (r >> 2) + 4 * (lane >> 5);
            float vi = ai[r] + bias_i;
            float vg = ag[r] + bias_g;
            float vo = ao[r] + bias_o;
            float si = fast_sigmoid(vi);
            float tg = fast_tanh(vg);
            float so = fast_sigmoid(vo);
            float c  = si * tg;
            float tc = fast_tanh(c);
            float h  = so * tc;
            const size_t off = (size_t)row * N_OUT + c0 + ln31;
            hout[off] = h;
            cout[off] = c;
        }
    }
}

extern "C" void kernel_launch(void* const* d_in, const int* in_sizes, int n_in,
                              void* d_out, int out_size, void* d_ws, size_t ws_size,
                              hipStream_t stream) {
    const float* x   = (const float*)d_in[0];
    const float* Wih = (const float*)d_in[1];
    // d_in[2] = W_hh is dead (h_prev == 0)
    const float* bih = (const float*)d_in[3];
    const float* bhh = (const float*)d_in[4];
    float* hout = (float*)d_out;
    float* cout = hout + (size_t)M_TOTAL * N_OUT;

    lstm_gates_kernel<<<NBLOCKS, 256, 0, stream>>>(x, Wih, bih, bhh, hout, cout);
}

// Round 3
// 339.779 us; speedup vs baseline: 1.1745x; 1.1745x over previous
//
#include <hip/hip_runtime.h>
#include <hip/hip_bf16.h>
#include <stdint.h>

// gates = x @ W_ih^T + b_ih + b_hh ; c = sig(i)*tanh(g) ; h = sig(o)*tanh(c)
// x: (131072,128) f32. Only gate rows i:[0,256) g:[512,768) o:[768,1024) used.
// out: h (131072,256) f32 then c (131072,256) f32.

#define M_TOTAL   (64 * 2048)
#define K_DIM     128
#define N_OUT     256
#define TILE_ROWS 64
#define TILE_BYTES (TILE_ROWS * K_DIM * 4)      // 32 KB
#define NBLK      256
#define ITERS     (M_TOTAL / TILE_ROWS / NBLK)  // 8

typedef __bf16 bf16x8 __attribute__((ext_vector_type(8)));
typedef float  f32x16 __attribute__((ext_vector_type(16)));

static __device__ __forceinline__ bf16x8 cvt8(float4 a, float4 b) {
    bf16x8 r;
    r[0] = (__bf16)a.x; r[1] = (__bf16)a.y; r[2] = (__bf16)a.z; r[3] = (__bf16)a.w;
    r[4] = (__bf16)b.x; r[5] = (__bf16)b.y; r[6] = (__bf16)b.z; r[7] = (__bf16)b.w;
    return r;
}

static __device__ __forceinline__ float fast_sigmoid(float x) {
    float e = __expf(-x);
    return __builtin_amdgcn_rcpf(1.0f + e);
}

static __device__ __forceinline__ float fast_tanh(float x) {
    float e = __expf(2.0f * x);
    return 1.0f - 2.0f * __builtin_amdgcn_rcpf(e + 1.0f);
}

static __device__ __forceinline__ void gload_lds16(const void* g, void* l) {
    __builtin_amdgcn_global_load_lds(
        (const __attribute__((address_space(1))) void*)g,
        (__attribute__((address_space(3))) void*)l, 16, 0, 0);
}

__global__ __launch_bounds__(512, 2)
void lstm_gates_kernel(const float* __restrict__ x,
                       const float* __restrict__ Wih,
                       const float* __restrict__ bih,
                       const float* __restrict__ bhh,
                       float* __restrict__ hout,
                       float* __restrict__ cout)
{
    __shared__ uint8_t lds[3 * TILE_BYTES];     // 96 KB, triple-buffered x tiles

    const int tid   = threadIdx.x;
    const int lane  = tid & 63;
    const int w     = tid >> 6;                 // wave id = 32-col gate slice
    const int c0    = w * 32;
    const int ln31  = lane & 31;
    const int khalf = (lane >> 5) * 8;          // k offset per half-wave
    const uint32_t xr = (uint32_t)(ln31 & 7) << 4;  // read-side XOR (row bits into 16B slot)

    // ---- W_ih fragments for gates i, g, o — registers, loaded once ----
    // B frag (32x32x16): col = lane&31, k-slots = kk*16 + khalf + j  (A uses the
    // same k-placement bijection, so the MFMA dot product is correct).
    bf16x8 bi[8], bg[8], bo[8];
    {
        const float4* wi = (const float4*)(Wih + (size_t)(0   + c0 + ln31) * K_DIM + khalf);
        const float4* wg = (const float4*)(Wih + (size_t)(512 + c0 + ln31) * K_DIM + khalf);
        const float4* wo = (const float4*)(Wih + (size_t)(768 + c0 + ln31) * K_DIM + khalf);
        #pragma unroll
        for (int kk = 0; kk < 8; ++kk) {
            bi[kk] = cvt8(wi[kk * 4], wi[kk * 4 + 1]);
            bg[kk] = cvt8(wg[kk * 4], wg[kk * 4 + 1]);
            bo[kk] = cvt8(wo[kk * 4], wo[kk * 4 + 1]);
        }
    }
    const float bias_i = bih[0   + c0 + ln31] + bhh[0   + c0 + ln31];
    const float bias_g = bih[512 + c0 + ln31] + bhh[512 + c0 + ln31];
    const float bias_o = bih[768 + c0 + ln31] + bhh[768 + c0 + ln31];

    const int t0 = blockIdx.x * ITERS;

    // Stage tile t into buffer buf: linear LDS dest (wave-uniform base + lane*16),
    // inverse-swizzled global source (rule #21: both-sides-or-neither).
    auto stage = [&](int buf, int t) {
        const uint8_t* gbase = (const uint8_t*)x + (size_t)t * TILE_BYTES;
        uint8_t* lbase = lds + (size_t)buf * TILE_BYTES + (size_t)w * 4096;
        #pragma unroll
        for (int j = 0; j < 4; ++j) {
            uint32_t d   = (uint32_t)w * 4096u + (uint32_t)j * 1024u + (uint32_t)lane * 16u;
            uint32_t src = d ^ (((d >> 9) & 7u) << 4);   // involution
            gload_lds16(gbase + src, lbase + (uint32_t)j * 1024u);
        }
    };

    auto compute = [&](int buf, int t) {
        const uint8_t* lbase = lds + (size_t)buf * TILE_BYTES;
        #pragma unroll
        for (int s = 0; s < 2; ++s) {
            const uint8_t* rowp = lbase + (uint32_t)(s * 32 + ln31) * 512u;
            bf16x8 a[8];
            #pragma unroll
            for (int kk = 0; kk < 8; ++kk) {
                const uint32_t off0 = (uint32_t)khalf * 4u + (uint32_t)kk * 64u;
                float4 lo = *(const float4*)(rowp + ((off0      ) ^ xr));
                float4 hi = *(const float4*)(rowp + ((off0 + 16u) ^ xr));
                a[kk] = cvt8(lo, hi);
            }
            f32x16 ai = (f32x16)0.0f, ag = (f32x16)0.0f, ao = (f32x16)0.0f;
            #pragma unroll
            for (int kk = 0; kk < 8; ++kk) {
                ai = __builtin_amdgcn_mfma_f32_32x32x16_bf16(a[kk], bi[kk], ai, 0, 0, 0);
                ag = __builtin_amdgcn_mfma_f32_32x32x16_bf16(a[kk], bg[kk], ag, 0, 0, 0);
                ao = __builtin_amdgcn_mfma_f32_32x32x16_bf16(a[kk], bo[kk], ao, 0, 0, 0);
            }
            const int m0 = t * TILE_ROWS + s * 32;
            // C/D layout: col = c0 + (lane&31), row = m0 + (r&3) + 8*(r>>2) + 4*(lane>>5)
            #pragma unroll
            for (int r = 0; r < 16; ++r) {
                const int row = m0 + (r & 3) + 8 * (r >> 2) + 4 * (lane >> 5);
                float vi = ai[r] + bias_i;
                float vg = ag[r] + bias_g;
                float vo = ao[r] + bias_o;
                float si = fast_sigmoid(vi);
                float tg = fast_tanh(vg);
                float so = fast_sigmoid(vo);
                float c  = si * tg;
                float tc = fast_tanh(c);
                float h  = so * tc;
                const size_t off = (size_t)row * N_OUT + c0 + ln31;
                hout[off] = h;
                cout[off] = c;
            }
        }
    };

    // Schedule: sync_i publishes buf[i%3] (staged in iter i-1) AND protects
    // buf[(i+1)%3] (last read in iter i-2, two syncs ago). Prefetch issued
    // right after the sync overlaps compute(i); it drains at sync_{i+1}.
    stage(0, t0);
    for (int i = 0; i < ITERS; ++i) {
        __syncthreads();
        if (i + 1 < ITERS) stage((i + 1) % 3, t0 + i + 1);
        compute(i % 3, t0 + i);
    }
}

extern "C" void kernel_launch(void* const* d_in, const int* in_sizes, int n_in,
                              void* d_out, int out_size, void* d_ws, size_t ws_size,
                              hipStream_t stream) {
    const float* x   = (const float*)d_in[0];
    const float* Wih = (const float*)d_in[1];
    // d_in[2] = W_hh is dead (h_prev == 0)
    const float* bih = (const float*)d_in[3];
    const float* bhh = (const float*)d_in[4];
    float* hout = (float*)d_out;
    float* cout = hout + (size_t)M_TOTAL * N_OUT;

    lstm_gates_kernel<<<NBLK, 512, 0, stream>>>(x, Wih, bih, bhh, hout, cout);
}